// Round 2
// baseline (254.175 us; speedup 1.0000x reference)
//
#include <hip/hip_runtime.h>
#include <stdint.h>
#include <math.h>

// B=2 S=2048 E=1024 H=16 DH=64 ROT=32 CTX=2048
// d_in / d_out are FLOAT32 (per reference). Internals use bf16 MFMA.
typedef __bf16 bf16x8 __attribute__((ext_vector_type(8)));
typedef float f32x4 __attribute__((ext_vector_type(4)));

__device__ __forceinline__ float bf2f(uint16_t x) {
  unsigned u = ((unsigned)x) << 16;
  float f;
  __builtin_memcpy(&f, &u, 4);
  return f;
}
// native RTNE f32->bf16
__device__ __forceinline__ uint16_t f2bf(float f) {
  __bf16 h = (__bf16)f;
  uint16_t u;
  __builtin_memcpy(&u, &h, 2);
  return u;
}
// load 8 contiguous f32, round to bf16x8
__device__ __forceinline__ bf16x8 cvt8(const float* p) {
  const float4 lo = *(const float4*)p;
  const float4 hi = *(const float4*)(p + 4);
  bf16x8 v;
  v[0] = (__bf16)lo.x; v[1] = (__bf16)lo.y; v[2] = (__bf16)lo.z; v[3] = (__bf16)lo.w;
  v[4] = (__bf16)hi.x; v[5] = (__bf16)hi.y; v[6] = (__bf16)hi.z; v[7] = (__bf16)hi.w;
  return v;
}

// direct global->LDS, 16B/lane; LDS dest = wave-uniform base + lane*16
typedef __attribute__((address_space(1))) const unsigned int gu32;
typedef __attribute__((address_space(3))) unsigned int lu32;
__device__ __forceinline__ void async_copy16(const void* gp, void* lp) {
  __builtin_amdgcn_global_load_lds((gu32*)gp, (lu32*)lp, 16, 0, 0);
}

// f32 -> bf16 elementwise convert (1M elems per z slice; grid.x=512)
__global__ __launch_bounds__(256) void cvt_kernel(
    const float* __restrict__ s0, uint16_t* __restrict__ d0,
    const float* __restrict__ s1, uint16_t* __restrict__ d1,
    const float* __restrict__ s2, uint16_t* __restrict__ d2) {
  const int z = blockIdx.z;
  const float* s = z == 0 ? s0 : z == 1 ? s1 : s2;
  uint16_t* d = z == 0 ? d0 : z == 1 ? d1 : d2;
  const size_t idx = ((size_t)blockIdx.x * 256 + threadIdx.x) * 8;
  *(bf16x8*)(d + idx) = cvt8(s + idx);
}

// NT GEMM + bias: C[m,n] = sum_k A[m,k]*W[n,k] + bias[n]
// BM x (NF*32) tile, BK=64, 256 threads as 2m x 2n waves, acc[BM/32][NF].
// R11 post-mortem: 128x128 tile + rotated prefetch REGRESSED (occupancy
// 31%->16%, VGPR 60->100, MfmaUtil 15->12) — these dispatches are
// concurrency-bound, not MFMA-density-bound. QKV stays at the measured-best
// BM=128/NF=2 (1536 blocks = 6/CU). R12: out-proj moves to BM=64 (was
// 128x64 at only 512 blocks = 2/CU, 8 waves/CU — the least-parallel
// dispatch in the pipeline) -> 1024 blocks = 4/CU, 16 waves/CU.
// LDS XOR-swizzled: conflict-free (0 measured) and contiguous rows
// (global_load_lds-compatible). m-fastest block map for XCD L2 locality.
// ROPE: fused into the bf16 epilogue for dh<32 (wave-uniform (wn+j*16)&63;
// pair partner in lane l16^1 -> shfl_xor). VT: z==2 writes C^T per-head.
template <bool A_F32, bool W_F32, bool C_F32, bool VT, bool ROPE, int BM, int NF>
__global__ __launch_bounds__(256) void gemm3_kernel(
    const void* __restrict__ A0, const void* __restrict__ W0,
    const float* __restrict__ b0, void* __restrict__ C0,
    const void* __restrict__ A1, const void* __restrict__ W1,
    const float* __restrict__ b1, void* __restrict__ C1,
    const void* __restrict__ A2, const void* __restrict__ W2,
    const float* __restrict__ b2, void* __restrict__ C2,
    int M, int N, int K) {
  constexpr int BN = NF * 32;
  constexpr int AF = BM / 32;   // A frags per wave, also A staging iters
  const int z = blockIdx.z;
  const void* Av = z == 0 ? A0 : z == 1 ? A1 : A2;
  const void* Wp = z == 0 ? W0 : z == 1 ? W1 : W2;
  const float* bias = z == 0 ? b0 : z == 1 ? b1 : b2;
  void* Cv = z == 0 ? C0 : z == 1 ? C1 : C2;

  __shared__ __align__(16) uint16_t As[BM * 64];
  __shared__ __align__(16) uint16_t Bs[BN * 64];
  const int tid = threadIdx.x;
  const int wave = tid >> 6, lane = tid & 63;
  const int quad = lane >> 4, l16 = lane & 15;
  // XCD-locality swizzle: m fastest in HW dispatch order
  const int l = blockIdx.y * gridDim.x + blockIdx.x;
  const int nmt = M / BM;
  const int bm = (l % nmt) * BM;
  const int bn = (l / nmt) * BN;
  const int wm = (wave >> 1) * (BM / 2);
  const int wn = (wave & 1) * (BN / 2);

  f32x4 acc[AF][NF] = {};

  for (int k0 = 0; k0 < K; k0 += 64) {
    bf16x8 ar[AF], wr[NF];
    if (A_F32) {
#pragma unroll
      for (int i = 0; i < AF; i++) {
        const int c = i * 256 + tid;
        const int r = c >> 3, pc = ((c & 7) ^ (r & 7)) << 3;
        ar[i] = cvt8((const float*)Av + (size_t)(bm + r) * K + k0 + pc);
      }
    }
    if (W_F32) {
#pragma unroll
      for (int i = 0; i < NF; i++) {
        const int c = i * 256 + tid;
        const int r = c >> 3, pc = ((c & 7) ^ (r & 7)) << 3;
        wr[i] = cvt8((const float*)Wp + (size_t)(bn + r) * K + k0 + pc);
      }
    }
    if (k0) __syncthreads();
#pragma unroll
    for (int i = 0; i < AF; i++) {
      const int c = i * 256 + tid;
      const int r = c >> 3, pc = ((c & 7) ^ (r & 7)) << 3;
      if (A_F32) *(bf16x8*)(As + c * 8) = ar[i];
      else async_copy16((const uint16_t*)Av + (size_t)(bm + r) * K + k0 + pc,
                        As + (i * 256 + (tid & 192)) * 8);
    }
#pragma unroll
    for (int i = 0; i < NF; i++) {
      const int c = i * 256 + tid;
      const int r = c >> 3, pc = ((c & 7) ^ (r & 7)) << 3;
      if (W_F32) *(bf16x8*)(Bs + c * 8) = wr[i];
      else async_copy16((const uint16_t*)Wp + (size_t)(bn + r) * K + k0 + pc,
                        Bs + (i * 256 + (tid & 192)) * 8);
    }
    __syncthreads();
#pragma unroll
    for (int s = 0; s < 2; s++) {
      bf16x8 af[AF], bfr[NF];
#pragma unroll
      for (int i = 0; i < AF; i++) {
        const int Ra = wm + i * 16 + l16;
        af[i] = *(const bf16x8*)(As + Ra * 64 + (((s * 4 + quad) ^ (Ra & 7)) << 3));
      }
#pragma unroll
      for (int j = 0; j < NF; j++) {
        const int Rb = wn + j * 16 + l16;
        bfr[j] = *(const bf16x8*)(Bs + Rb * 64 + (((s * 4 + quad) ^ (Rb & 7)) << 3));
      }
#pragma unroll
      for (int i = 0; i < AF; i++)
#pragma unroll
        for (int j = 0; j < NF; j++)
          acc[i][j] = __builtin_amdgcn_mfma_f32_16x16x32_bf16(af[i], bfr[j], acc[i][j], 0, 0, 0);
    }
  }
  if (VT && z == 2) {
#pragma unroll
    for (int j = 0; j < NF; j++) {
      const int n = bn + wn + j * 16 + l16;
      const float bj = bias[n];
      const int h = n >> 6, dh = n & 63;
#pragma unroll
      for (int i = 0; i < AF; i++) {
        const int m0 = bm + wm + i * 16 + quad * 4;
        const int b = m0 >> 11, s0 = m0 & 2047;
        uint2 pk;
        pk.x = (unsigned)f2bf(acc[i][j][0] + bj) |
               ((unsigned)f2bf(acc[i][j][1] + bj) << 16);
        pk.y = (unsigned)f2bf(acc[i][j][2] + bj) |
               ((unsigned)f2bf(acc[i][j][3] + bj) << 16);
        *(uint2*)((uint16_t*)Cv + ((size_t)((b * 16 + h) * 64 + dh)) * 2048 + s0) = pk;
      }
    }
  } else {
#pragma unroll
    for (int j = 0; j < NF; j++) {
      const int n = bn + wn + j * 16 + l16;
      const float bj = bias[n];
      // dh = n & 63; rot iff dh<32 — wave-uniform: ((wn + j*16) & 63) < 32
      const int dh = (wn + j * 16 + l16) & 63;
      const bool rot = ROPE && (((wn + j * 16) & 63) < 32);
      float invrev = 0.f;
      if (rot)
        invrev = __expf(-0.5756462732485115f * (float)(dh >> 1)) *
                 0.15915494309189535f;  // 10000^(-i/16) / 2pi
#pragma unroll
      for (int i = 0; i < AF; i++) {
        const int m0 = bm + wm + i * 16 + quad * 4;
#pragma unroll
        for (int r = 0; r < 4; r++) {
          float v = acc[i][j][r] + bj;
          if (rot) {
            const int s_pos = (m0 + r) & 2047;
            float rev = (float)s_pos * invrev;
            rev -= floorf(rev);
            const float sn = __builtin_amdgcn_sinf(rev);
            const float cs = __builtin_amdgcn_cosf(rev);
            const float partner = __shfl_xor(v, 1);
            v = (dh & 1) ? (v * cs + partner * sn) : (v * cs - partner * sn);
          }
          if (C_F32) ((float*)Cv)[(size_t)(m0 + r) * N + n] = v;
          else       ((uint16_t*)Cv)[(size_t)(m0 + r) * N + n] = f2bf(v);
        }
      }
    }
  }
}

// Flash attention, causal, MAX-FREE softmax (scores statically bounded ->
// exp finite; masked lanes -1e30 -> exp=0). S^T form: lane l16 owns q-row
// l16; P pack = 4x ds_write_b64; one scalar row-sum per frag.
// 128 q-rows per block (2 Q-frags per wave). Low frag fully masked at the
// last kt -> skipped. XCD swizzle: bx&7 = XCD; 4 heads/XCD -> 2 MB K/VT
// L2-resident (R8: FETCH dropped to ~unique bytes).
__global__ __launch_bounds__(256) void flash_kernel(const uint16_t* __restrict__ Q,
                                                    const uint16_t* __restrict__ K,
                                                    const uint16_t* __restrict__ VT,
                                                    uint16_t* __restrict__ AO) {
  const int bx = blockIdx.x;           // 512 blocks
  const int xcd = bx & 7;
  const int slot = bx >> 3;            // 0..63
  const int bh = (slot >> 4) * 8 + xcd;
  const int qt2 = 15 - (slot & 15);    // heaviest first
  const int h = bh & 15;
  const int b = bh >> 4;
  const int tid = threadIdx.x;
  const int wave = tid >> 6, lane = tid & 63;
  const int quad = lane >> 4, l16 = lane & 15;

  __shared__ __align__(16) uint16_t Ks[64 * 64];      // [n][d] swizzled
  __shared__ __align__(16) uint16_t Vt[64 * 64];      // [d][n] swizzled
  __shared__ __align__(16) uint16_t Ps[4][32 * 72];   // per-wave P (2 frags)

  // Q fragments (B-operand layout: lane l16 = q-row), pre-scaled by 1/8
  const int qrow0 = qt2 * 128 + wave * 16 + l16;      // frag0
  const int qrow1 = qrow0 + 64;                       // frag1
  bf16x8 qf0[2], qf1[2];
#pragma unroll
  for (int s = 0; s < 2; s++) {
    union { bf16x8 v; uint16_t u[8]; } t0, t1;
    t0.v = *(const bf16x8*)(Q + ((size_t)(b * 2048 + qrow0) * 1024) + h * 64 + s * 32 + quad * 8);
    t1.v = *(const bf16x8*)(Q + ((size_t)(b * 2048 + qrow1) * 1024) + h * 64 + s * 32 + quad * 8);
#pragma unroll
    for (int j = 0; j < 8; j++) {
      t0.u[j] = f2bf(bf2f(t0.u[j]) * 0.125f);
      t1.u[j] = f2bf(bf2f(t1.u[j]) * 0.125f);
    }
    qf0[s] = t0.v;
    qf1[s] = t1.v;
  }

  const size_t vbase = ((size_t)((b * 16 + h) * 64)) * 2048;  // VT head base

  float lsum0 = 0.f, lsum1 = 0.f;
  f32x4 o0[4] = {}, o1[4] = {};

  const int nkt = 2 * qt2 + 2;
  for (int kt = 0; kt < nkt; kt++) {
    if (kt) __syncthreads();
#pragma unroll
    for (int i = 0; i < 2; i++) {
      const int c = i * 256 + tid;
      const int r = c >> 3, pc = ((c & 7) ^ (r & 7)) << 3;
      async_copy16(K + ((size_t)(b * 2048 + kt * 64 + r) * 1024) + h * 64 + pc,
                   Ks + (i * 256 + (tid & 192)) * 8);
      async_copy16(VT + vbase + (size_t)r * 2048 + kt * 64 + pc,
                   Vt + (i * 256 + (tid & 192)) * 8);
    }
    __syncthreads();

    const bool f0 = (kt < nkt - 1);  // low frag fully masked at last kt

    // ---- frag1 S^T ----
    {
      f32x4 sacc[4] = {};
#pragma unroll
      for (int s = 0; s < 2; s++)
#pragma unroll
        for (int t = 0; t < 4; t++) {
          const int R = t * 16 + l16;
          bf16x8 kf = *(const bf16x8*)(Ks + R * 64 + (((s * 4 + quad) ^ (R & 7)) << 3));
          sacc[t] = __builtin_amdgcn_mfma_f32_16x16x32_bf16(kf, qf1[s], sacc[t], 0, 0, 0);
        }
      if (kt == nkt - 1) {
#pragma unroll
        for (int t = 0; t < 4; t++)
#pragma unroll
          for (int r = 0; r < 4; r++)
            if (kt * 64 + t * 16 + quad * 4 + r > qrow1) sacc[t][r] = -1e30f;
      }
#pragma unroll
      for (int t = 0; t < 4; t++) {
        float p0 = __expf(sacc[t][0]), p1 = __expf(sacc[t][1]);
        float p2 = __expf(sacc[t][2]), p3 = __expf(sacc[t][3]);
        lsum1 += (p0 + p1) + (p2 + p3);
        uint2 pk;
        pk.x = (unsigned)f2bf(p0) | ((unsigned)f2bf(p1) << 16);
        pk.y = (unsigned)f2bf(p2) | ((unsigned)f2bf(p3) << 16);
        *(uint2*)(&Ps[wave][(16 + l16) * 72 + t * 16 + quad * 4]) = pk;
      }
    }
    // ---- frag0 S^T ----
    if (f0) {
      f32x4 sacc[4] = {};
#pragma unroll
      for (int s = 0; s < 2; s++)
#pragma unroll
        for (int t = 0; t < 4; t++) {
          const int R = t * 16 + l16;
          bf16x8 kf = *(const bf16x8*)(Ks + R * 64 + (((s * 4 + quad) ^ (R & 7)) << 3));
          sacc[t] = __builtin_amdgcn_mfma_f32_16x16x32_bf16(kf, qf0[s], sacc[t], 0, 0, 0);
        }
      if (kt == nkt - 2) {
#pragma unroll
        for (int t = 0; t < 4; t++)
#pragma unroll
          for (int r = 0; r < 4; r++)
            if (kt * 64 + t * 16 + quad * 4 + r > qrow0) sacc[t][r] = -1e30f;
      }
#pragma unroll
      for (int t = 0; t < 4; t++) {
        float p0 = __expf(sacc[t][0]), p1 = __expf(sacc[t][1]);
        float p2 = __expf(sacc[t][2]), p3 = __expf(sacc[t][3]);
        lsum0 += (p0 + p1) + (p2 + p3);
        uint2 pk;
        pk.x = (unsigned)f2bf(p0) | ((unsigned)f2bf(p1) << 16);
        pk.y = (unsigned)f2bf(p2) | ((unsigned)f2bf(p3) << 16);
        *(uint2*)(&Ps[wave][l16 * 72 + t * 16 + quad * 4]) = pk;
      }
    }
    // ---- PV ----
#pragma unroll
    for (int s = 0; s < 2; s++) {
      const bf16x8 pa1 = *(const bf16x8*)(&Ps[wave][(16 + l16) * 72 + s * 32 + quad * 8]);
#pragma unroll
      for (int t = 0; t < 4; t++) {
        const int R = t * 16 + l16;
        const bf16x8 vb = *(const bf16x8*)(Vt + R * 64 + (((s * 4 + quad) ^ (R & 7)) << 3));
        o1[t] = __builtin_amdgcn_mfma_f32_16x16x32_bf16(pa1, vb, o1[t], 0, 0, 0);
      }
    }
    if (f0) {
#pragma unroll
      for (int s = 0; s < 2; s++) {
        const bf16x8 pa0 = *(const bf16x8*)(&Ps[wave][l16 * 72 + s * 32 + quad * 8]);
#pragma unroll
        for (int t = 0; t < 4; t++) {
          const int R = t * 16 + l16;
          const bf16x8 vb = *(const bf16x8*)(Vt + R * 64 + (((s * 4 + quad) ^ (R & 7)) << 3));
          o0[t] = __builtin_amdgcn_mfma_f32_16x16x32_bf16(pa0, vb, o0[t], 0, 0, 0);
        }
      }
    }
  }
  // row-sum reduce over quads (q-row = l16); broadcast inverse to C/D rows
  lsum0 += __shfl_xor(lsum0, 16);
  lsum0 += __shfl_xor(lsum0, 32);
  lsum1 += __shfl_xor(lsum1, 16);
  lsum1 += __shfl_xor(lsum1, 32);
  const float inv0 = 1.f / lsum0, inv1 = 1.f / lsum1;
  float invr0[4], invr1[4];
#pragma unroll
  for (int r = 0; r < 4; r++) {
    invr0[r] = __shfl(inv0, quad * 4 + r);
    invr1[r] = __shfl(inv1, quad * 4 + r);
  }
#pragma unroll
  for (int t = 0; t < 4; t++)
#pragma unroll
    for (int r = 0; r < 4; r++) {
      const int qg0 = qt2 * 128 + wave * 16 + quad * 4 + r;
      AO[((size_t)(b * 2048 + qg0) * 1024) + h * 64 + t * 16 + l16] =
          f2bf(o0[t][r] * invr0[r]);
      AO[((size_t)(b * 2048 + qg0 + 64) * 1024) + h * 64 + t * 16 + l16] =
          f2bf(o1[t][r] * invr1[r]);
    }
}

extern "C" void kernel_launch(void* const* d_in, const int* in_sizes, int n_in,
                              void* d_out, int out_size, void* d_ws, size_t ws_size,
                              hipStream_t stream) {
  const float* query = (const float*)d_in[0];
  const float* key   = (const float*)d_in[1];
  const float* value = (const float*)d_in[2];
  const float* Wq = (const float*)d_in[3];
  const float* bq = (const float*)d_in[4];
  const float* Wk = (const float*)d_in[5];
  const float* bk = (const float*)d_in[6];
  const float* Wv = (const float*)d_in[7];
  const float* bv = (const float*)d_in[8];
  const float* Wo = (const float*)d_in[9];
  const float* bo = (const float*)d_in[10];
  float* out = (float*)d_out;

  uint16_t* ws = (uint16_t*)d_ws;
  uint16_t* Qb  = ws;                         // [0,4M) bf16 (roped)
  uint16_t* Kb  = ws + (size_t)4194304;       // [4M,8M) (roped)
  uint16_t* VTb = ws + (size_t)8388608;       // [8M,12M) V^T [b,h,d,s]
  uint16_t* AOb = ws + (size_t)12582912;      // [12M,16M) — total 32 MB
  // bf16 W copies live inside AOb; consumed by QKV GEMM before flash
  // overwrites AOb (stream-ordered).
  uint16_t* Wqc = AOb;
  uint16_t* Wkc = AOb + (size_t)1048576;
  uint16_t* Wvc = AOb + (size_t)2097152;

  dim3 blk(256);
  cvt_kernel<<<dim3(512, 1, 3), blk, 0, stream>>>(Wq, Wqc, Wk, Wkc, Wv, Wvc);
  // QKV: 128x64 tile (measured best: 1536 blocks = 6/CU)
  gemm3_kernel<true, false, false, true, true, 128, 2><<<dim3(16, 32, 3), blk, 0, stream>>>(
      query, Wqc, bq, Qb,
      key,   Wkc, bk, Kb,
      value, Wvc, bv, VTb,
      4096, 1024, 1024);
  flash_kernel<<<dim3(512), blk, 0, stream>>>(Qb, Kb, VTb, AOb);
  // out-proj: 64x64 tile -> 1024 blocks = 4/CU, 16 waves/CU (was 512 = 2/CU)
  gemm3_kernel<false, true, true, false, false, 64, 2><<<dim3(16, 64, 1), blk, 0, stream>>>(
      AOb, Wo, bo, out,
      AOb, Wo, bo, out,
      AOb, Wo, bo, out,
      4096, 1024, 1024);
}

// Round 3
// 242.959 us; speedup vs baseline: 1.0462x; 1.0462x over previous
//
#include <hip/hip_runtime.h>
#include <stdint.h>
#include <math.h>

// B=2 S=2048 E=1024 H=16 DH=64 ROT=32 CTX=2048
// d_in / d_out are FLOAT32 (per reference). Internals use bf16 MFMA.
typedef __bf16 bf16x8 __attribute__((ext_vector_type(8)));
typedef float f32x4 __attribute__((ext_vector_type(4)));

__device__ __forceinline__ float bf2f(uint16_t x) {
  unsigned u = ((unsigned)x) << 16;
  float f;
  __builtin_memcpy(&f, &u, 4);
  return f;
}
// native RTNE f32->bf16
__device__ __forceinline__ uint16_t f2bf(float f) {
  __bf16 h = (__bf16)f;
  uint16_t u;
  __builtin_memcpy(&u, &h, 2);
  return u;
}
// round two float4s to bf16x8
__device__ __forceinline__ bf16x8 pack8(float4 lo, float4 hi) {
  bf16x8 v;
  v[0] = (__bf16)lo.x; v[1] = (__bf16)lo.y; v[2] = (__bf16)lo.z; v[3] = (__bf16)lo.w;
  v[4] = (__bf16)hi.x; v[5] = (__bf16)hi.y; v[6] = (__bf16)hi.z; v[7] = (__bf16)hi.w;
  return v;
}
// load 8 contiguous f32, round to bf16x8
__device__ __forceinline__ bf16x8 cvt8(const float* p) {
  return pack8(*(const float4*)p, *(const float4*)(p + 4));
}

// direct global->LDS, 16B/lane; LDS dest = wave-uniform base + lane*16
typedef __attribute__((address_space(1))) const unsigned int gu32;
typedef __attribute__((address_space(3))) unsigned int lu32;
__device__ __forceinline__ void async_copy16(const void* gp, void* lp) {
  __builtin_amdgcn_global_load_lds((gu32*)gp, (lu32*)lp, 16, 0, 0);
}

// f32 -> bf16 elementwise convert (1M elems per z slice; grid.x=512)
__global__ __launch_bounds__(256) void cvt_kernel(
    const float* __restrict__ s0, uint16_t* __restrict__ d0,
    const float* __restrict__ s1, uint16_t* __restrict__ d1,
    const float* __restrict__ s2, uint16_t* __restrict__ d2) {
  const int z = blockIdx.z;
  const float* s = z == 0 ? s0 : z == 1 ? s1 : s2;
  uint16_t* d = z == 0 ? d0 : z == 1 ? d1 : d2;
  const size_t idx = ((size_t)blockIdx.x * 256 + threadIdx.x) * 8;
  *(bf16x8*)(d + idx) = cvt8(s + idx);
}

// NT GEMM + bias: C[m,n] = sum_k A[m,k]*W[n,k] + bias[n]
// BM x (NF*32) tile, BK=64, 256 threads as 2m x 2n waves, acc[BM/32][NF].
// R13: A_F32 path rebuilt — f32 A-tile goes global->LDS via global_load_lds
// (NO register staging: R1 showed reg-prefetch kills occupancy; R0's
// reg-staging exposes f32 load latency at the barrier). f32->bf16 happens
// on the fragment-read path (2x ds_read_b128 + cvt_pk per frag). LDS unit
// swizzle u_lds = u_g ^ (row&7) on 16B units: involution applied to the
// pre-swizzled GLOBAL source (LDS dest linear, as global_load_lds needs)
// and to the read; fragment pairs stay adjacent (XOR can't split an
// even/odd 16B pair), bank distribution identical to the proven-0-conflict
// bf16 layout. With DMA-only staging the 128x128 tile is safe (m97-style:
// 3 blocks/CU suffices when no reg staging) -> 32 MFMA/K-step/wave.
// W_F32 (out-proj) keeps the R0 reg-staged path (measured best there).
// m-fastest block map for XCD L2 locality.
// ROPE: fused into the bf16 epilogue for dh<32 (wave-uniform (wn+j*16)&63;
// pair partner in lane l16^1 -> shfl_xor). VT: z==2 writes C^T per-head.
template <bool A_F32, bool W_F32, bool C_F32, bool VT, bool ROPE, int BM, int NF>
__global__ __launch_bounds__(256) void gemm3_kernel(
    const void* __restrict__ A0, const void* __restrict__ W0,
    const float* __restrict__ b0, void* __restrict__ C0,
    const void* __restrict__ A1, const void* __restrict__ W1,
    const float* __restrict__ b1, void* __restrict__ C1,
    const void* __restrict__ A2, const void* __restrict__ W2,
    const float* __restrict__ b2, void* __restrict__ C2,
    int M, int N, int K) {
  constexpr int BN = NF * 32;
  constexpr int AF = BM / 32;   // A frags per wave
  const int z = blockIdx.z;
  const void* Av = z == 0 ? A0 : z == 1 ? A1 : A2;
  const void* Wp = z == 0 ? W0 : z == 1 ? W1 : W2;
  const float* bias = z == 0 ? b0 : z == 1 ? b1 : b2;
  void* Cv = z == 0 ? C0 : z == 1 ? C1 : C2;

  // A region: f32 tile (BM x 64 f32 = BM*128 u16) or bf16 tile (BM*64 u16)
  __shared__ __align__(16) uint16_t As[BM * (A_F32 ? 128 : 64)];
  __shared__ __align__(16) uint16_t Bs[BN * 64];
  const int tid = threadIdx.x;
  const int wave = tid >> 6, lane = tid & 63;
  const int quad = lane >> 4, l16 = lane & 15;
  // XCD-locality swizzle: m fastest in HW dispatch order
  const int l = blockIdx.y * gridDim.x + blockIdx.x;
  const int nmt = M / BM;
  const int bm = (l % nmt) * BM;
  const int bn = (l / nmt) * BN;
  const int wm = (wave >> 1) * (BM / 2);
  const int wn = (wave & 1) * (BN / 2);

  f32x4 acc[AF][NF] = {};

  for (int k0 = 0; k0 < K; k0 += 64) {
    bf16x8 wr[NF];
    if (W_F32) {
#pragma unroll
      for (int i = 0; i < NF; i++) {
        const int c = i * 256 + tid;
        const int r = c >> 3, pc = ((c & 7) ^ (r & 7)) << 3;
        wr[i] = cvt8((const float*)Wp + (size_t)(bn + r) * K + k0 + pc);
      }
    }
    if (k0) __syncthreads();
    if (A_F32) {
      // f32 tile: BM rows x 16 16B-units/row; pre-swizzled global source
#pragma unroll
      for (int i = 0; i < BM / 16; i++) {
        const int U = i * 256 + tid;
        const int r = U >> 4, ug = (U & 15) ^ (r & 7);
        async_copy16((const float*)Av + (size_t)(bm + r) * K + k0 + ug * 4,
                     As + (i * 256 + (tid & 192)) * 8);
      }
    } else {
#pragma unroll
      for (int i = 0; i < AF; i++) {
        const int c = i * 256 + tid;
        const int r = c >> 3, pc = ((c & 7) ^ (r & 7)) << 3;
        async_copy16((const uint16_t*)Av + (size_t)(bm + r) * K + k0 + pc,
                     As + (i * 256 + (tid & 192)) * 8);
      }
    }
#pragma unroll
    for (int i = 0; i < NF; i++) {
      const int c = i * 256 + tid;
      const int r = c >> 3, pc = ((c & 7) ^ (r & 7)) << 3;
      if (W_F32) *(bf16x8*)(Bs + c * 8) = wr[i];
      else async_copy16((const uint16_t*)Wp + (size_t)(bn + r) * K + k0 + pc,
                        Bs + (i * 256 + (tid & 192)) * 8);
    }
    __syncthreads();
#pragma unroll
    for (int s = 0; s < 2; s++) {
      bf16x8 af[AF], bfr[NF];
#pragma unroll
      for (int i = 0; i < AF; i++) {
        const int Ra = wm + i * 16 + l16;
        if (A_F32) {
          const float* Asf = (const float*)As;
          // global f32 units (2*(s*4+quad), +1) -> lds units g, g^1
          const int g = ((s * 4 + quad) * 2) ^ (Ra & 7);
          const float4 lo = *(const float4*)(Asf + Ra * 64 + g * 4);
          const float4 hi = *(const float4*)(Asf + Ra * 64 + (g ^ 1) * 4);
          af[i] = pack8(lo, hi);
        } else {
          af[i] = *(const bf16x8*)(As + Ra * 64 + (((s * 4 + quad) ^ (Ra & 7)) << 3));
        }
      }
#pragma unroll
      for (int j = 0; j < NF; j++) {
        const int Rb = wn + j * 16 + l16;
        bfr[j] = *(const bf16x8*)(Bs + Rb * 64 + (((s * 4 + quad) ^ (Rb & 7)) << 3));
      }
#pragma unroll
      for (int i = 0; i < AF; i++)
#pragma unroll
        for (int j = 0; j < NF; j++)
          acc[i][j] = __builtin_amdgcn_mfma_f32_16x16x32_bf16(af[i], bfr[j], acc[i][j], 0, 0, 0);
    }
  }
  if (VT && z == 2) {
#pragma unroll
    for (int j = 0; j < NF; j++) {
      const int n = bn + wn + j * 16 + l16;
      const float bj = bias[n];
      const int h = n >> 6, dh = n & 63;
#pragma unroll
      for (int i = 0; i < AF; i++) {
        const int m0 = bm + wm + i * 16 + quad * 4;
        const int b = m0 >> 11, s0 = m0 & 2047;
        uint2 pk;
        pk.x = (unsigned)f2bf(acc[i][j][0] + bj) |
               ((unsigned)f2bf(acc[i][j][1] + bj) << 16);
        pk.y = (unsigned)f2bf(acc[i][j][2] + bj) |
               ((unsigned)f2bf(acc[i][j][3] + bj) << 16);
        *(uint2*)((uint16_t*)Cv + ((size_t)((b * 16 + h) * 64 + dh)) * 2048 + s0) = pk;
      }
    }
  } else {
#pragma unroll
    for (int j = 0; j < NF; j++) {
      const int n = bn + wn + j * 16 + l16;
      const float bj = bias[n];
      // dh = n & 63; rot iff dh<32 — wave-uniform: ((wn + j*16) & 63) < 32
      const int dh = (wn + j * 16 + l16) & 63;
      const bool rot = ROPE && (((wn + j * 16) & 63) < 32);
      float invrev = 0.f;
      if (rot)
        invrev = __expf(-0.5756462732485115f * (float)(dh >> 1)) *
                 0.15915494309189535f;  // 10000^(-i/16) / 2pi
#pragma unroll
      for (int i = 0; i < AF; i++) {
        const int m0 = bm + wm + i * 16 + quad * 4;
#pragma unroll
        for (int r = 0; r < 4; r++) {
          float v = acc[i][j][r] + bj;
          if (rot) {
            const int s_pos = (m0 + r) & 2047;
            float rev = (float)s_pos * invrev;
            rev -= floorf(rev);
            const float sn = __builtin_amdgcn_sinf(rev);
            const float cs = __builtin_amdgcn_cosf(rev);
            const float partner = __shfl_xor(v, 1);
            v = (dh & 1) ? (v * cs + partner * sn) : (v * cs - partner * sn);
          }
          if (C_F32) ((float*)Cv)[(size_t)(m0 + r) * N + n] = v;
          else       ((uint16_t*)Cv)[(size_t)(m0 + r) * N + n] = f2bf(v);
        }
      }
    }
  }
}

// Flash attention, causal, MAX-FREE softmax (scores statically bounded ->
// exp finite; masked lanes -1e30 -> exp=0). S^T form: lane l16 owns q-row
// l16; P pack = 4x ds_write_b64; one scalar row-sum per frag.
// 128 q-rows per block (2 Q-frags per wave). Low frag fully masked at the
// last kt -> skipped. XCD swizzle: bx&7 = XCD; 4 heads/XCD -> 2 MB K/VT
// L2-resident (R8: FETCH dropped to ~unique bytes).
__global__ __launch_bounds__(256) void flash_kernel(const uint16_t* __restrict__ Q,
                                                    const uint16_t* __restrict__ K,
                                                    const uint16_t* __restrict__ VT,
                                                    uint16_t* __restrict__ AO) {
  const int bx = blockIdx.x;           // 512 blocks
  const int xcd = bx & 7;
  const int slot = bx >> 3;            // 0..63
  const int bh = (slot >> 4) * 8 + xcd;
  const int qt2 = 15 - (slot & 15);    // heaviest first
  const int h = bh & 15;
  const int b = bh >> 4;
  const int tid = threadIdx.x;
  const int wave = tid >> 6, lane = tid & 63;
  const int quad = lane >> 4, l16 = lane & 15;

  __shared__ __align__(16) uint16_t Ks[64 * 64];      // [n][d] swizzled
  __shared__ __align__(16) uint16_t Vt[64 * 64];      // [d][n] swizzled
  __shared__ __align__(16) uint16_t Ps[4][32 * 72];   // per-wave P (2 frags)

  // Q fragments (B-operand layout: lane l16 = q-row), pre-scaled by 1/8
  const int qrow0 = qt2 * 128 + wave * 16 + l16;      // frag0
  const int qrow1 = qrow0 + 64;                       // frag1
  bf16x8 qf0[2], qf1[2];
#pragma unroll
  for (int s = 0; s < 2; s++) {
    union { bf16x8 v; uint16_t u[8]; } t0, t1;
    t0.v = *(const bf16x8*)(Q + ((size_t)(b * 2048 + qrow0) * 1024) + h * 64 + s * 32 + quad * 8);
    t1.v = *(const bf16x8*)(Q + ((size_t)(b * 2048 + qrow1) * 1024) + h * 64 + s * 32 + quad * 8);
#pragma unroll
    for (int j = 0; j < 8; j++) {
      t0.u[j] = f2bf(bf2f(t0.u[j]) * 0.125f);
      t1.u[j] = f2bf(bf2f(t1.u[j]) * 0.125f);
    }
    qf0[s] = t0.v;
    qf1[s] = t1.v;
  }

  const size_t vbase = ((size_t)((b * 16 + h) * 64)) * 2048;  // VT head base

  float lsum0 = 0.f, lsum1 = 0.f;
  f32x4 o0[4] = {}, o1[4] = {};

  const int nkt = 2 * qt2 + 2;
  for (int kt = 0; kt < nkt; kt++) {
    if (kt) __syncthreads();
#pragma unroll
    for (int i = 0; i < 2; i++) {
      const int c = i * 256 + tid;
      const int r = c >> 3, pc = ((c & 7) ^ (r & 7)) << 3;
      async_copy16(K + ((size_t)(b * 2048 + kt * 64 + r) * 1024) + h * 64 + pc,
                   Ks + (i * 256 + (tid & 192)) * 8);
      async_copy16(VT + vbase + (size_t)r * 2048 + kt * 64 + pc,
                   Vt + (i * 256 + (tid & 192)) * 8);
    }
    __syncthreads();

    const bool f0 = (kt < nkt - 1);  // low frag fully masked at last kt

    // ---- frag1 S^T ----
    {
      f32x4 sacc[4] = {};
#pragma unroll
      for (int s = 0; s < 2; s++)
#pragma unroll
        for (int t = 0; t < 4; t++) {
          const int R = t * 16 + l16;
          bf16x8 kf = *(const bf16x8*)(Ks + R * 64 + (((s * 4 + quad) ^ (R & 7)) << 3));
          sacc[t] = __builtin_amdgcn_mfma_f32_16x16x32_bf16(kf, qf1[s], sacc[t], 0, 0, 0);
        }
      if (kt == nkt - 1) {
#pragma unroll
        for (int t = 0; t < 4; t++)
#pragma unroll
          for (int r = 0; r < 4; r++)
            if (kt * 64 + t * 16 + quad * 4 + r > qrow1) sacc[t][r] = -1e30f;
      }
#pragma unroll
      for (int t = 0; t < 4; t++) {
        float p0 = __expf(sacc[t][0]), p1 = __expf(sacc[t][1]);
        float p2 = __expf(sacc[t][2]), p3 = __expf(sacc[t][3]);
        lsum1 += (p0 + p1) + (p2 + p3);
        uint2 pk;
        pk.x = (unsigned)f2bf(p0) | ((unsigned)f2bf(p1) << 16);
        pk.y = (unsigned)f2bf(p2) | ((unsigned)f2bf(p3) << 16);
        *(uint2*)(&Ps[wave][(16 + l16) * 72 + t * 16 + quad * 4]) = pk;
      }
    }
    // ---- frag0 S^T ----
    if (f0) {
      f32x4 sacc[4] = {};
#pragma unroll
      for (int s = 0; s < 2; s++)
#pragma unroll
        for (int t = 0; t < 4; t++) {
          const int R = t * 16 + l16;
          bf16x8 kf = *(const bf16x8*)(Ks + R * 64 + (((s * 4 + quad) ^ (R & 7)) << 3));
          sacc[t] = __builtin_amdgcn_mfma_f32_16x16x32_bf16(kf, qf0[s], sacc[t], 0, 0, 0);
        }
      if (kt == nkt - 2) {
#pragma unroll
        for (int t = 0; t < 4; t++)
#pragma unroll
          for (int r = 0; r < 4; r++)
            if (kt * 64 + t * 16 + quad * 4 + r > qrow0) sacc[t][r] = -1e30f;
      }
#pragma unroll
      for (int t = 0; t < 4; t++) {
        float p0 = __expf(sacc[t][0]), p1 = __expf(sacc[t][1]);
        float p2 = __expf(sacc[t][2]), p3 = __expf(sacc[t][3]);
        lsum0 += (p0 + p1) + (p2 + p3);
        uint2 pk;
        pk.x = (unsigned)f2bf(p0) | ((unsigned)f2bf(p1) << 16);
        pk.y = (unsigned)f2bf(p2) | ((unsigned)f2bf(p3) << 16);
        *(uint2*)(&Ps[wave][l16 * 72 + t * 16 + quad * 4]) = pk;
      }
    }
    // ---- PV ----
#pragma unroll
    for (int s = 0; s < 2; s++) {
      const bf16x8 pa1 = *(const bf16x8*)(&Ps[wave][(16 + l16) * 72 + s * 32 + quad * 8]);
#pragma unroll
      for (int t = 0; t < 4; t++) {
        const int R = t * 16 + l16;
        const bf16x8 vb = *(const bf16x8*)(Vt + R * 64 + (((s * 4 + quad) ^ (R & 7)) << 3));
        o1[t] = __builtin_amdgcn_mfma_f32_16x16x32_bf16(pa1, vb, o1[t], 0, 0, 0);
      }
    }
    if (f0) {
#pragma unroll
      for (int s = 0; s < 2; s++) {
        const bf16x8 pa0 = *(const bf16x8*)(&Ps[wave][l16 * 72 + s * 32 + quad * 8]);
#pragma unroll
        for (int t = 0; t < 4; t++) {
          const int R = t * 16 + l16;
          const bf16x8 vb = *(const bf16x8*)(Vt + R * 64 + (((s * 4 + quad) ^ (R & 7)) << 3));
          o0[t] = __builtin_amdgcn_mfma_f32_16x16x32_bf16(pa0, vb, o0[t], 0, 0, 0);
        }
      }
    }
  }
  // row-sum reduce over quads (q-row = l16); broadcast inverse to C/D rows
  lsum0 += __shfl_xor(lsum0, 16);
  lsum0 += __shfl_xor(lsum0, 32);
  lsum1 += __shfl_xor(lsum1, 16);
  lsum1 += __shfl_xor(lsum1, 32);
  const float inv0 = 1.f / lsum0, inv1 = 1.f / lsum1;
  float invr0[4], invr1[4];
#pragma unroll
  for (int r = 0; r < 4; r++) {
    invr0[r] = __shfl(inv0, quad * 4 + r);
    invr1[r] = __shfl(inv1, quad * 4 + r);
  }
#pragma unroll
  for (int t = 0; t < 4; t++)
#pragma unroll
    for (int r = 0; r < 4; r++) {
      const int qg0 = qt2 * 128 + wave * 16 + quad * 4 + r;
      AO[((size_t)(b * 2048 + qg0) * 1024) + h * 64 + t * 16 + l16] =
          f2bf(o0[t][r] * invr0[r]);
      AO[((size_t)(b * 2048 + qg0 + 64) * 1024) + h * 64 + t * 16 + l16] =
          f2bf(o1[t][r] * invr1[r]);
    }
}

extern "C" void kernel_launch(void* const* d_in, const int* in_sizes, int n_in,
                              void* d_out, int out_size, void* d_ws, size_t ws_size,
                              hipStream_t stream) {
  const float* query = (const float*)d_in[0];
  const float* key   = (const float*)d_in[1];
  const float* value = (const float*)d_in[2];
  const float* Wq = (const float*)d_in[3];
  const float* bq = (const float*)d_in[4];
  const float* Wk = (const float*)d_in[5];
  const float* bk = (const float*)d_in[6];
  const float* Wv = (const float*)d_in[7];
  const float* bv = (const float*)d_in[8];
  const float* Wo = (const float*)d_in[9];
  const float* bo = (const float*)d_in[10];
  float* out = (float*)d_out;

  uint16_t* ws = (uint16_t*)d_ws;
  uint16_t* Qb  = ws;                         // [0,4M) bf16 (roped)
  uint16_t* Kb  = ws + (size_t)4194304;       // [4M,8M) (roped)
  uint16_t* VTb = ws + (size_t)8388608;       // [8M,12M) V^T [b,h,d,s]
  uint16_t* AOb = ws + (size_t)12582912;      // [12M,16M) — total 32 MB
  // bf16 W copies live inside AOb; consumed by QKV GEMM before flash
  // overwrites AOb (stream-ordered).
  uint16_t* Wqc = AOb;
  uint16_t* Wkc = AOb + (size_t)1048576;
  uint16_t* Wvc = AOb + (size_t)2097152;

  dim3 blk(256);
  cvt_kernel<<<dim3(512, 1, 3), blk, 0, stream>>>(Wq, Wqc, Wk, Wkc, Wv, Wvc);
  // QKV: 128x128 tile, f32-A via global_load_lds, bf16-W via global_load_lds
  // grid 8 n-tiles x 32 m-tiles x 3 = 768 blocks = 3/CU (LDS 48KB)
  gemm3_kernel<true, false, false, true, true, 128, 4><<<dim3(8, 32, 3), blk, 0, stream>>>(
      query, Wqc, bq, Qb,
      key,   Wkc, bk, Kb,
      value, Wvc, bv, VTb,
      4096, 1024, 1024);
  flash_kernel<<<dim3(512), blk, 0, stream>>>(Qb, Kb, VTb, AOb);
  // out-proj: exact R0 config (128x64, W f32 reg-staged) — measured best
  gemm3_kernel<false, true, true, false, false, 128, 2><<<dim3(16, 32, 1), blk, 0, stream>>>(
      AOb, Wo, bo, out,
      AOb, Wo, bo, out,
      AOb, Wo, bo, out,
      4096, 1024, 1024);
}

// Round 4
// 230.048 us; speedup vs baseline: 1.1049x; 1.0561x over previous
//
#include <hip/hip_runtime.h>
#include <stdint.h>
#include <math.h>

// B=2 S=2048 E=1024 H=16 DH=64 ROT=32 CTX=2048
// d_in / d_out are FLOAT32 (per reference). Internals use bf16 MFMA.
typedef __bf16 bf16x8 __attribute__((ext_vector_type(8)));
typedef float f32x4 __attribute__((ext_vector_type(4)));

__device__ __forceinline__ float bf2f(uint16_t x) {
  unsigned u = ((unsigned)x) << 16;
  float f;
  __builtin_memcpy(&f, &u, 4);
  return f;
}
// native RTNE f32->bf16
__device__ __forceinline__ uint16_t f2bf(float f) {
  __bf16 h = (__bf16)f;
  uint16_t u;
  __builtin_memcpy(&u, &h, 2);
  return u;
}
// round two float4s to bf16x8
__device__ __forceinline__ bf16x8 pack8(float4 lo, float4 hi) {
  bf16x8 v;
  v[0] = (__bf16)lo.x; v[1] = (__bf16)lo.y; v[2] = (__bf16)lo.z; v[3] = (__bf16)lo.w;
  v[4] = (__bf16)hi.x; v[5] = (__bf16)hi.y; v[6] = (__bf16)hi.z; v[7] = (__bf16)hi.w;
  return v;
}
// load 8 contiguous f32, round to bf16x8
__device__ __forceinline__ bf16x8 cvt8(const float* p) {
  return pack8(*(const float4*)p, *(const float4*)(p + 4));
}

// direct global->LDS, 16B/lane; LDS dest = wave-uniform base + lane*16
typedef __attribute__((address_space(1))) const unsigned int gu32;
typedef __attribute__((address_space(3))) unsigned int lu32;
__device__ __forceinline__ void async_copy16(const void* gp, void* lp) {
  __builtin_amdgcn_global_load_lds((gu32*)gp, (lu32*)lp, 16, 0, 0);
}

// f32 -> bf16 elementwise convert; grid.z selects tensor, grid.x*256*8 = count
__global__ __launch_bounds__(256) void cvt_kernel(
    const float* __restrict__ s0, uint16_t* __restrict__ d0,
    const float* __restrict__ s1, uint16_t* __restrict__ d1,
    const float* __restrict__ s2, uint16_t* __restrict__ d2,
    const float* __restrict__ s3, uint16_t* __restrict__ d3) {
  const int z = blockIdx.z;
  const float* s = z == 0 ? s0 : z == 1 ? s1 : z == 2 ? s2 : s3;
  uint16_t* d = z == 0 ? d0 : z == 1 ? d1 : z == 2 ? d2 : d3;
  const size_t idx = ((size_t)blockIdx.x * 256 + threadIdx.x) * 8;
  *(bf16x8*)(d + idx) = cvt8(s + idx);
}

// NT GEMM + bias: C[m,n] = sum_k A[m,k]*W[n,k] + bias[n]
// BM x (NF*32) tile, BK=64, 256 threads as 2m x 2n waves, acc[BM/32][NF].
// R14: pure-bf16 both-operand global_load_lds path (A_F32=W_F32=false) is
// the m97-proven config: 0.25 KB staged / MFMA (vs 0.375 for any f32
// operand — R3 showed dur tracks staged-bytes-per-MFMA, not MFMA count).
// 128x128 QKV tile = 32KB LDS = 5 blocks/CU, zero reg staging.
// A_F32/W_F32 reg-staged paths retained for the ws_size<64MB fallback
// (exact R0 config, measured 243 µs).
// LDS XOR-swizzled: conflict-free (0 measured) and contiguous rows
// (global_load_lds-compatible). m-fastest block map for XCD L2 locality.
// ROPE: fused into the bf16 epilogue for dh<32 (wave-uniform (wn+j*16)&63;
// pair partner in lane l16^1 -> shfl_xor). VT: z==2 writes C^T per-head.
template <bool A_F32, bool W_F32, bool C_F32, bool VT, bool ROPE, int BM, int NF>
__global__ __launch_bounds__(256) void gemm3_kernel(
    const void* __restrict__ A0, const void* __restrict__ W0,
    const float* __restrict__ b0, void* __restrict__ C0,
    const void* __restrict__ A1, const void* __restrict__ W1,
    const float* __restrict__ b1, void* __restrict__ C1,
    const void* __restrict__ A2, const void* __restrict__ W2,
    const float* __restrict__ b2, void* __restrict__ C2,
    int M, int N, int K) {
  constexpr int BN = NF * 32;
  constexpr int AF = BM / 32;   // A frags per wave, also A staging iters
  const int z = blockIdx.z;
  const void* Av = z == 0 ? A0 : z == 1 ? A1 : A2;
  const void* Wp = z == 0 ? W0 : z == 1 ? W1 : W2;
  const float* bias = z == 0 ? b0 : z == 1 ? b1 : b2;
  void* Cv = z == 0 ? C0 : z == 1 ? C1 : C2;

  __shared__ __align__(16) uint16_t As[BM * 64];
  __shared__ __align__(16) uint16_t Bs[BN * 64];
  const int tid = threadIdx.x;
  const int wave = tid >> 6, lane = tid & 63;
  const int quad = lane >> 4, l16 = lane & 15;
  // XCD-locality swizzle: m fastest in HW dispatch order
  const int l = blockIdx.y * gridDim.x + blockIdx.x;
  const int nmt = M / BM;
  const int bm = (l % nmt) * BM;
  const int bn = (l / nmt) * BN;
  const int wm = (wave >> 1) * (BM / 2);
  const int wn = (wave & 1) * (BN / 2);

  f32x4 acc[AF][NF] = {};

  for (int k0 = 0; k0 < K; k0 += 64) {
    bf16x8 ar[AF], wr[NF];
    if (A_F32) {
#pragma unroll
      for (int i = 0; i < AF; i++) {
        const int c = i * 256 + tid;
        const int r = c >> 3, pc = ((c & 7) ^ (r & 7)) << 3;
        ar[i] = cvt8((const float*)Av + (size_t)(bm + r) * K + k0 + pc);
      }
    }
    if (W_F32) {
#pragma unroll
      for (int i = 0; i < NF; i++) {
        const int c = i * 256 + tid;
        const int r = c >> 3, pc = ((c & 7) ^ (r & 7)) << 3;
        wr[i] = cvt8((const float*)Wp + (size_t)(bn + r) * K + k0 + pc);
      }
    }
    if (k0) __syncthreads();
#pragma unroll
    for (int i = 0; i < AF; i++) {
      const int c = i * 256 + tid;
      const int r = c >> 3, pc = ((c & 7) ^ (r & 7)) << 3;
      if (A_F32) *(bf16x8*)(As + c * 8) = ar[i];
      else async_copy16((const uint16_t*)Av + (size_t)(bm + r) * K + k0 + pc,
                        As + (i * 256 + (tid & 192)) * 8);
    }
#pragma unroll
    for (int i = 0; i < NF; i++) {
      const int c = i * 256 + tid;
      const int r = c >> 3, pc = ((c & 7) ^ (r & 7)) << 3;
      if (W_F32) *(bf16x8*)(Bs + c * 8) = wr[i];
      else async_copy16((const uint16_t*)Wp + (size_t)(bn + r) * K + k0 + pc,
                        Bs + (i * 256 + (tid & 192)) * 8);
    }
    __syncthreads();
#pragma unroll
    for (int s = 0; s < 2; s++) {
      bf16x8 af[AF], bfr[NF];
#pragma unroll
      for (int i = 0; i < AF; i++) {
        const int Ra = wm + i * 16 + l16;
        af[i] = *(const bf16x8*)(As + Ra * 64 + (((s * 4 + quad) ^ (Ra & 7)) << 3));
      }
#pragma unroll
      for (int j = 0; j < NF; j++) {
        const int Rb = wn + j * 16 + l16;
        bfr[j] = *(const bf16x8*)(Bs + Rb * 64 + (((s * 4 + quad) ^ (Rb & 7)) << 3));
      }
#pragma unroll
      for (int i = 0; i < AF; i++)
#pragma unroll
        for (int j = 0; j < NF; j++)
          acc[i][j] = __builtin_amdgcn_mfma_f32_16x16x32_bf16(af[i], bfr[j], acc[i][j], 0, 0, 0);
    }
  }
  if (VT && z == 2) {
#pragma unroll
    for (int j = 0; j < NF; j++) {
      const int n = bn + wn + j * 16 + l16;
      const float bj = bias[n];
      const int h = n >> 6, dh = n & 63;
#pragma unroll
      for (int i = 0; i < AF; i++) {
        const int m0 = bm + wm + i * 16 + quad * 4;
        const int b = m0 >> 11, s0 = m0 & 2047;
        uint2 pk;
        pk.x = (unsigned)f2bf(acc[i][j][0] + bj) |
               ((unsigned)f2bf(acc[i][j][1] + bj) << 16);
        pk.y = (unsigned)f2bf(acc[i][j][2] + bj) |
               ((unsigned)f2bf(acc[i][j][3] + bj) << 16);
        *(uint2*)((uint16_t*)Cv + ((size_t)((b * 16 + h) * 64 + dh)) * 2048 + s0) = pk;
      }
    }
  } else {
#pragma unroll
    for (int j = 0; j < NF; j++) {
      const int n = bn + wn + j * 16 + l16;
      const float bj = bias[n];
      // dh = n & 63; rot iff dh<32 — wave-uniform: ((wn + j*16) & 63) < 32
      const int dh = (wn + j * 16 + l16) & 63;
      const bool rot = ROPE && (((wn + j * 16) & 63) < 32);
      float invrev = 0.f;
      if (rot)
        invrev = __expf(-0.5756462732485115f * (float)(dh >> 1)) *
                 0.15915494309189535f;  // 10000^(-i/16) / 2pi
#pragma unroll
      for (int i = 0; i < AF; i++) {
        const int m0 = bm + wm + i * 16 + quad * 4;
#pragma unroll
        for (int r = 0; r < 4; r++) {
          float v = acc[i][j][r] + bj;
          if (rot) {
            const int s_pos = (m0 + r) & 2047;
            float rev = (float)s_pos * invrev;
            rev -= floorf(rev);
            const float sn = __builtin_amdgcn_sinf(rev);
            const float cs = __builtin_amdgcn_cosf(rev);
            const float partner = __shfl_xor(v, 1);
            v = (dh & 1) ? (v * cs + partner * sn) : (v * cs - partner * sn);
          }
          if (C_F32) ((float*)Cv)[(size_t)(m0 + r) * N + n] = v;
          else       ((uint16_t*)Cv)[(size_t)(m0 + r) * N + n] = f2bf(v);
        }
      }
    }
  }
}

// Flash attention, causal, MAX-FREE softmax (scores statically bounded ->
// exp finite; masked lanes -1e30 -> exp=0). S^T form: lane l16 owns q-row
// l16; P pack = 4x ds_write_b64; one scalar row-sum per frag.
// 128 q-rows per block (2 Q-frags per wave). Low frag fully masked at the
// last kt -> skipped. XCD swizzle: bx&7 = XCD; 4 heads/XCD -> 2 MB K/VT
// L2-resident (R8: FETCH dropped to ~unique bytes).
__global__ __launch_bounds__(256) void flash_kernel(const uint16_t* __restrict__ Q,
                                                    const uint16_t* __restrict__ K,
                                                    const uint16_t* __restrict__ VT,
                                                    uint16_t* __restrict__ AO) {
  const int bx = blockIdx.x;           // 512 blocks
  const int xcd = bx & 7;
  const int slot = bx >> 3;            // 0..63
  const int bh = (slot >> 4) * 8 + xcd;
  const int qt2 = 15 - (slot & 15);    // heaviest first
  const int h = bh & 15;
  const int b = bh >> 4;
  const int tid = threadIdx.x;
  const int wave = tid >> 6, lane = tid & 63;
  const int quad = lane >> 4, l16 = lane & 15;

  __shared__ __align__(16) uint16_t Ks[64 * 64];      // [n][d] swizzled
  __shared__ __align__(16) uint16_t Vt[64 * 64];      // [d][n] swizzled
  __shared__ __align__(16) uint16_t Ps[4][32 * 72];   // per-wave P (2 frags)

  // Q fragments (B-operand layout: lane l16 = q-row), pre-scaled by 1/8
  const int qrow0 = qt2 * 128 + wave * 16 + l16;      // frag0
  const int qrow1 = qrow0 + 64;                       // frag1
  bf16x8 qf0[2], qf1[2];
#pragma unroll
  for (int s = 0; s < 2; s++) {
    union { bf16x8 v; uint16_t u[8]; } t0, t1;
    t0.v = *(const bf16x8*)(Q + ((size_t)(b * 2048 + qrow0) * 1024) + h * 64 + s * 32 + quad * 8);
    t1.v = *(const bf16x8*)(Q + ((size_t)(b * 2048 + qrow1) * 1024) + h * 64 + s * 32 + quad * 8);
#pragma unroll
    for (int j = 0; j < 8; j++) {
      t0.u[j] = f2bf(bf2f(t0.u[j]) * 0.125f);
      t1.u[j] = f2bf(bf2f(t1.u[j]) * 0.125f);
    }
    qf0[s] = t0.v;
    qf1[s] = t1.v;
  }

  const size_t vbase = ((size_t)((b * 16 + h) * 64)) * 2048;  // VT head base

  float lsum0 = 0.f, lsum1 = 0.f;
  f32x4 o0[4] = {}, o1[4] = {};

  const int nkt = 2 * qt2 + 2;
  for (int kt = 0; kt < nkt; kt++) {
    if (kt) __syncthreads();
#pragma unroll
    for (int i = 0; i < 2; i++) {
      const int c = i * 256 + tid;
      const int r = c >> 3, pc = ((c & 7) ^ (r & 7)) << 3;
      async_copy16(K + ((size_t)(b * 2048 + kt * 64 + r) * 1024) + h * 64 + pc,
                   Ks + (i * 256 + (tid & 192)) * 8);
      async_copy16(VT + vbase + (size_t)r * 2048 + kt * 64 + pc,
                   Vt + (i * 256 + (tid & 192)) * 8);
    }
    __syncthreads();

    const bool f0 = (kt < nkt - 1);  // low frag fully masked at last kt

    // ---- frag1 S^T ----
    {
      f32x4 sacc[4] = {};
#pragma unroll
      for (int s = 0; s < 2; s++)
#pragma unroll
        for (int t = 0; t < 4; t++) {
          const int R = t * 16 + l16;
          bf16x8 kf = *(const bf16x8*)(Ks + R * 64 + (((s * 4 + quad) ^ (R & 7)) << 3));
          sacc[t] = __builtin_amdgcn_mfma_f32_16x16x32_bf16(kf, qf1[s], sacc[t], 0, 0, 0);
        }
      if (kt == nkt - 1) {
#pragma unroll
        for (int t = 0; t < 4; t++)
#pragma unroll
          for (int r = 0; r < 4; r++)
            if (kt * 64 + t * 16 + quad * 4 + r > qrow1) sacc[t][r] = -1e30f;
      }
#pragma unroll
      for (int t = 0; t < 4; t++) {
        float p0 = __expf(sacc[t][0]), p1 = __expf(sacc[t][1]);
        float p2 = __expf(sacc[t][2]), p3 = __expf(sacc[t][3]);
        lsum1 += (p0 + p1) + (p2 + p3);
        uint2 pk;
        pk.x = (unsigned)f2bf(p0) | ((unsigned)f2bf(p1) << 16);
        pk.y = (unsigned)f2bf(p2) | ((unsigned)f2bf(p3) << 16);
        *(uint2*)(&Ps[wave][(16 + l16) * 72 + t * 16 + quad * 4]) = pk;
      }
    }
    // ---- frag0 S^T ----
    if (f0) {
      f32x4 sacc[4] = {};
#pragma unroll
      for (int s = 0; s < 2; s++)
#pragma unroll
        for (int t = 0; t < 4; t++) {
          const int R = t * 16 + l16;
          bf16x8 kf = *(const bf16x8*)(Ks + R * 64 + (((s * 4 + quad) ^ (R & 7)) << 3));
          sacc[t] = __builtin_amdgcn_mfma_f32_16x16x32_bf16(kf, qf0[s], sacc[t], 0, 0, 0);
        }
      if (kt == nkt - 2) {
#pragma unroll
        for (int t = 0; t < 4; t++)
#pragma unroll
          for (int r = 0; r < 4; r++)
            if (kt * 64 + t * 16 + quad * 4 + r > qrow0) sacc[t][r] = -1e30f;
      }
#pragma unroll
      for (int t = 0; t < 4; t++) {
        float p0 = __expf(sacc[t][0]), p1 = __expf(sacc[t][1]);
        float p2 = __expf(sacc[t][2]), p3 = __expf(sacc[t][3]);
        lsum0 += (p0 + p1) + (p2 + p3);
        uint2 pk;
        pk.x = (unsigned)f2bf(p0) | ((unsigned)f2bf(p1) << 16);
        pk.y = (unsigned)f2bf(p2) | ((unsigned)f2bf(p3) << 16);
        *(uint2*)(&Ps[wave][l16 * 72 + t * 16 + quad * 4]) = pk;
      }
    }
    // ---- PV ----
#pragma unroll
    for (int s = 0; s < 2; s++) {
      const bf16x8 pa1 = *(const bf16x8*)(&Ps[wave][(16 + l16) * 72 + s * 32 + quad * 8]);
#pragma unroll
      for (int t = 0; t < 4; t++) {
        const int R = t * 16 + l16;
        const bf16x8 vb = *(const bf16x8*)(Vt + R * 64 + (((s * 4 + quad) ^ (R & 7)) << 3));
        o1[t] = __builtin_amdgcn_mfma_f32_16x16x32_bf16(pa1, vb, o1[t], 0, 0, 0);
      }
    }
    if (f0) {
#pragma unroll
      for (int s = 0; s < 2; s++) {
        const bf16x8 pa0 = *(const bf16x8*)(&Ps[wave][l16 * 72 + s * 32 + quad * 8]);
#pragma unroll
        for (int t = 0; t < 4; t++) {
          const int R = t * 16 + l16;
          const bf16x8 vb = *(const bf16x8*)(Vt + R * 64 + (((s * 4 + quad) ^ (R & 7)) << 3));
          o0[t] = __builtin_amdgcn_mfma_f32_16x16x32_bf16(pa0, vb, o0[t], 0, 0, 0);
        }
      }
    }
  }
  // row-sum reduce over quads (q-row = l16); broadcast inverse to C/D rows
  lsum0 += __shfl_xor(lsum0, 16);
  lsum0 += __shfl_xor(lsum0, 32);
  lsum1 += __shfl_xor(lsum1, 16);
  lsum1 += __shfl_xor(lsum1, 32);
  const float inv0 = 1.f / lsum0, inv1 = 1.f / lsum1;
  float invr0[4], invr1[4];
#pragma unroll
  for (int r = 0; r < 4; r++) {
    invr0[r] = __shfl(inv0, quad * 4 + r);
    invr1[r] = __shfl(inv1, quad * 4 + r);
  }
#pragma unroll
  for (int t = 0; t < 4; t++)
#pragma unroll
    for (int r = 0; r < 4; r++) {
      const int qg0 = qt2 * 128 + wave * 16 + quad * 4 + r;
      AO[((size_t)(b * 2048 + qg0) * 1024) + h * 64 + t * 16 + l16] =
          f2bf(o0[t][r] * invr0[r]);
      AO[((size_t)(b * 2048 + qg0 + 64) * 1024) + h * 64 + t * 16 + l16] =
          f2bf(o1[t][r] * invr1[r]);
    }
}

extern "C" void kernel_launch(void* const* d_in, const int* in_sizes, int n_in,
                              void* d_out, int out_size, void* d_ws, size_t ws_size,
                              hipStream_t stream) {
  const float* query = (const float*)d_in[0];
  const float* key   = (const float*)d_in[1];
  const float* value = (const float*)d_in[2];
  const float* Wq = (const float*)d_in[3];
  const float* bq = (const float*)d_in[4];
  const float* Wk = (const float*)d_in[5];
  const float* bk = (const float*)d_in[6];
  const float* Wv = (const float*)d_in[7];
  const float* bv = (const float*)d_in[8];
  const float* Wo = (const float*)d_in[9];
  const float* bo = (const float*)d_in[10];
  float* out = (float*)d_out;

  uint16_t* ws = (uint16_t*)d_ws;
  uint16_t* Qb  = ws;                         // [0,8M) bytes: bf16 (roped)
  uint16_t* Kb  = ws + (size_t)4194304;       // [8M,16M) (roped)
  uint16_t* VTb = ws + (size_t)8388608;       // [16M,24M) V^T [b,h,d,s]
  uint16_t* AOb = ws + (size_t)12582912;      // [24M,32M)

  dim3 blk(256);

  if (ws_size >= (size_t)64 * 1024 * 1024) {
    // Fast path: bf16 copies of activations + all weights -> pure-DMA GEMMs.
    uint16_t* Qc  = ws + (size_t)16777216;    // [32M,40M) query bf16
    uint16_t* Kc  = ws + (size_t)20971520;    // [40M,48M) key bf16
    uint16_t* Vc  = ws + (size_t)25165824;    // [48M,56M) value bf16
    uint16_t* Wqc = ws + (size_t)29360128;    // [56M,58M)
    uint16_t* Wkc = ws + (size_t)30408704;    // [58M,60M)
    uint16_t* Wvc = ws + (size_t)31457280;    // [60M,62M)
    uint16_t* Woc = ws + (size_t)32505856;    // [62M,64M)

    cvt_kernel<<<dim3(512, 1, 4), blk, 0, stream>>>(
        Wq, Wqc, Wk, Wkc, Wv, Wvc, Wo, Woc);
    cvt_kernel<<<dim3(2048, 1, 3), blk, 0, stream>>>(
        query, Qc, key, Kc, value, Vc, nullptr, nullptr);
    // QKV: pure bf16, 128x128 tile, both operands global_load_lds,
    // 32KB LDS -> 5 blocks/CU; grid 8 n-tiles x 32 m-tiles x 3
    gemm3_kernel<false, false, false, true, true, 128, 4><<<dim3(8, 32, 3), blk, 0, stream>>>(
        Qc, Wqc, bq, Qb,
        Kc, Wkc, bk, Kb,
        Vc, Wvc, bv, VTb,
        4096, 1024, 1024);
    flash_kernel<<<dim3(512), blk, 0, stream>>>(Qb, Kb, VTb, AOb);
    // out-proj: pure bf16 128x64, both DMA, 24KB LDS -> 6 blocks/CU
    gemm3_kernel<false, false, true, false, false, 128, 2><<<dim3(16, 32, 1), blk, 0, stream>>>(
        AOb, Woc, bo, out,
        AOb, Woc, bo, out,
        AOb, Woc, bo, out,
        4096, 1024, 1024);
  } else {
    // Fallback: exact R0 configuration (32MB workspace, measured 243 µs).
    uint16_t* Wqc = AOb;
    uint16_t* Wkc = AOb + (size_t)1048576;
    uint16_t* Wvc = AOb + (size_t)2097152;
    cvt_kernel<<<dim3(512, 1, 3), blk, 0, stream>>>(
        Wq, Wqc, Wk, Wkc, Wv, Wvc, nullptr, nullptr);
    gemm3_kernel<true, false, false, true, true, 128, 2><<<dim3(16, 32, 3), blk, 0, stream>>>(
        query, Wqc, bq, Qb,
        key,   Wkc, bk, Kb,
        value, Wvc, bv, VTb,
        4096, 1024, 1024);
    flash_kernel<<<dim3(512), blk, 0, stream>>>(Qb, Kb, VTb, AOb);
    gemm3_kernel<false, true, true, false, false, 128, 2><<<dim3(16, 32, 1), blk, 0, stream>>>(
        AOb, Wo, bo, out,
        AOb, Wo, bo, out,
        AOb, Wo, bo, out,
        4096, 1024, 1024);
  }
}

// Round 5
// 229.804 us; speedup vs baseline: 1.1061x; 1.0011x over previous
//
#include <hip/hip_runtime.h>
#include <stdint.h>
#include <math.h>

// B=2 S=2048 E=1024 H=16 DH=64 ROT=32 CTX=2048
// d_in / d_out are FLOAT32 (per reference). Internals use bf16 MFMA.
typedef __bf16 bf16x8 __attribute__((ext_vector_type(8)));
typedef float f32x4 __attribute__((ext_vector_type(4)));

__device__ __forceinline__ float bf2f(uint16_t x) {
  unsigned u = ((unsigned)x) << 16;
  float f;
  __builtin_memcpy(&f, &u, 4);
  return f;
}
// native RTNE f32->bf16
__device__ __forceinline__ uint16_t f2bf(float f) {
  __bf16 h = (__bf16)f;
  uint16_t u;
  __builtin_memcpy(&u, &h, 2);
  return u;
}
// round two float4s to bf16x8
__device__ __forceinline__ bf16x8 pack8(float4 lo, float4 hi) {
  bf16x8 v;
  v[0] = (__bf16)lo.x; v[1] = (__bf16)lo.y; v[2] = (__bf16)lo.z; v[3] = (__bf16)lo.w;
  v[4] = (__bf16)hi.x; v[5] = (__bf16)hi.y; v[6] = (__bf16)hi.z; v[7] = (__bf16)hi.w;
  return v;
}
// load 8 contiguous f32, round to bf16x8
__device__ __forceinline__ bf16x8 cvt8(const float* p) {
  return pack8(*(const float4*)p, *(const float4*)(p + 4));
}

// direct global->LDS, 16B/lane; LDS dest = wave-uniform base + lane*16
typedef __attribute__((address_space(1))) const unsigned int gu32;
typedef __attribute__((address_space(3))) unsigned int lu32;
__device__ __forceinline__ void async_copy16(const void* gp, void* lp) {
  __builtin_amdgcn_global_load_lds((gu32*)gp, (lu32*)lp, 16, 0, 0);
}

// f32 -> bf16 elementwise convert; grid.z selects tensor, grid.x*256*8 = count
__global__ __launch_bounds__(256) void cvt_kernel(
    const float* __restrict__ s0, uint16_t* __restrict__ d0,
    const float* __restrict__ s1, uint16_t* __restrict__ d1,
    const float* __restrict__ s2, uint16_t* __restrict__ d2,
    const float* __restrict__ s3, uint16_t* __restrict__ d3) {
  const int z = blockIdx.z;
  const float* s = z == 0 ? s0 : z == 1 ? s1 : z == 2 ? s2 : s3;
  uint16_t* d = z == 0 ? d0 : z == 1 ? d1 : z == 2 ? d2 : d3;
  const size_t idx = ((size_t)blockIdx.x * 256 + threadIdx.x) * 8;
  *(bf16x8*)(d + idx) = cvt8(s + idx);
}

// NT GEMM + bias: C[m,n] = sum_k A[m,k]*W[n,k] + bias[n]
// BM x (NF*32) tile, BK=64, 256 threads as 2m x 2n waves, acc[BM/32][NF].
// R14: pure-bf16 both-operand global_load_lds path (A_F32=W_F32=false) is
// the m97-proven config: 0.25 KB staged / MFMA (vs 0.375 for any f32
// operand — R3 showed dur tracks staged-bytes-per-MFMA, not MFMA count).
// 128x128 QKV tile = 32KB LDS = 5 blocks/CU, zero reg staging.
// A_F32/W_F32 reg-staged paths retained for the ws_size<64MB fallback.
// LDS XOR-swizzled: conflict-free (0 measured) and contiguous rows
// (global_load_lds-compatible). m-fastest block map for XCD L2 locality.
// ROPE: fused into the bf16 epilogue for dh<32 (wave-uniform (wn+j*16)&63;
// pair partner in lane l16^1 -> shfl_xor). VT: z==2 writes C^T per-head.
template <bool A_F32, bool W_F32, bool C_F32, bool VT, bool ROPE, int BM, int NF>
__global__ __launch_bounds__(256) void gemm3_kernel(
    const void* __restrict__ A0, const void* __restrict__ W0,
    const float* __restrict__ b0, void* __restrict__ C0,
    const void* __restrict__ A1, const void* __restrict__ W1,
    const float* __restrict__ b1, void* __restrict__ C1,
    const void* __restrict__ A2, const void* __restrict__ W2,
    const float* __restrict__ b2, void* __restrict__ C2,
    int M, int N, int K) {
  constexpr int BN = NF * 32;
  constexpr int AF = BM / 32;   // A frags per wave, also A staging iters
  const int z = blockIdx.z;
  const void* Av = z == 0 ? A0 : z == 1 ? A1 : A2;
  const void* Wp = z == 0 ? W0 : z == 1 ? W1 : W2;
  const float* bias = z == 0 ? b0 : z == 1 ? b1 : b2;
  void* Cv = z == 0 ? C0 : z == 1 ? C1 : C2;

  __shared__ __align__(16) uint16_t As[BM * 64];
  __shared__ __align__(16) uint16_t Bs[BN * 64];
  const int tid = threadIdx.x;
  const int wave = tid >> 6, lane = tid & 63;
  const int quad = lane >> 4, l16 = lane & 15;
  // XCD-locality swizzle: m fastest in HW dispatch order
  const int l = blockIdx.y * gridDim.x + blockIdx.x;
  const int nmt = M / BM;
  const int bm = (l % nmt) * BM;
  const int bn = (l / nmt) * BN;
  const int wm = (wave >> 1) * (BM / 2);
  const int wn = (wave & 1) * (BN / 2);

  f32x4 acc[AF][NF] = {};

  for (int k0 = 0; k0 < K; k0 += 64) {
    bf16x8 ar[AF], wr[NF];
    if (A_F32) {
#pragma unroll
      for (int i = 0; i < AF; i++) {
        const int c = i * 256 + tid;
        const int r = c >> 3, pc = ((c & 7) ^ (r & 7)) << 3;
        ar[i] = cvt8((const float*)Av + (size_t)(bm + r) * K + k0 + pc);
      }
    }
    if (W_F32) {
#pragma unroll
      for (int i = 0; i < NF; i++) {
        const int c = i * 256 + tid;
        const int r = c >> 3, pc = ((c & 7) ^ (r & 7)) << 3;
        wr[i] = cvt8((const float*)Wp + (size_t)(bn + r) * K + k0 + pc);
      }
    }
    if (k0) __syncthreads();
#pragma unroll
    for (int i = 0; i < AF; i++) {
      const int c = i * 256 + tid;
      const int r = c >> 3, pc = ((c & 7) ^ (r & 7)) << 3;
      if (A_F32) *(bf16x8*)(As + c * 8) = ar[i];
      else async_copy16((const uint16_t*)Av + (size_t)(bm + r) * K + k0 + pc,
                        As + (i * 256 + (tid & 192)) * 8);
    }
#pragma unroll
    for (int i = 0; i < NF; i++) {
      const int c = i * 256 + tid;
      const int r = c >> 3, pc = ((c & 7) ^ (r & 7)) << 3;
      if (W_F32) *(bf16x8*)(Bs + c * 8) = wr[i];
      else async_copy16((const uint16_t*)Wp + (size_t)(bn + r) * K + k0 + pc,
                        Bs + (i * 256 + (tid & 192)) * 8);
    }
    __syncthreads();
#pragma unroll
    for (int s = 0; s < 2; s++) {
      bf16x8 af[AF], bfr[NF];
#pragma unroll
      for (int i = 0; i < AF; i++) {
        const int Ra = wm + i * 16 + l16;
        af[i] = *(const bf16x8*)(As + Ra * 64 + (((s * 4 + quad) ^ (Ra & 7)) << 3));
      }
#pragma unroll
      for (int j = 0; j < NF; j++) {
        const int Rb = wn + j * 16 + l16;
        bfr[j] = *(const bf16x8*)(Bs + Rb * 64 + (((s * 4 + quad) ^ (Rb & 7)) << 3));
      }
#pragma unroll
      for (int i = 0; i < AF; i++)
#pragma unroll
        for (int j = 0; j < NF; j++)
          acc[i][j] = __builtin_amdgcn_mfma_f32_16x16x32_bf16(af[i], bfr[j], acc[i][j], 0, 0, 0);
    }
  }
  if (VT && z == 2) {
#pragma unroll
    for (int j = 0; j < NF; j++) {
      const int n = bn + wn + j * 16 + l16;
      const float bj = bias[n];
      const int h = n >> 6, dh = n & 63;
#pragma unroll
      for (int i = 0; i < AF; i++) {
        const int m0 = bm + wm + i * 16 + quad * 4;
        const int b = m0 >> 11, s0 = m0 & 2047;
        uint2 pk;
        pk.x = (unsigned)f2bf(acc[i][j][0] + bj) |
               ((unsigned)f2bf(acc[i][j][1] + bj) << 16);
        pk.y = (unsigned)f2bf(acc[i][j][2] + bj) |
               ((unsigned)f2bf(acc[i][j][3] + bj) << 16);
        *(uint2*)((uint16_t*)Cv + ((size_t)((b * 16 + h) * 64 + dh)) * 2048 + s0) = pk;
      }
    }
  } else {
#pragma unroll
    for (int j = 0; j < NF; j++) {
      const int n = bn + wn + j * 16 + l16;
      const float bj = bias[n];
      // dh = n & 63; rot iff dh<32 — wave-uniform: ((wn + j*16) & 63) < 32
      const int dh = (wn + j * 16 + l16) & 63;
      const bool rot = ROPE && (((wn + j * 16) & 63) < 32);
      float invrev = 0.f;
      if (rot)
        invrev = __expf(-0.5756462732485115f * (float)(dh >> 1)) *
                 0.15915494309189535f;  // 10000^(-i/16) / 2pi
#pragma unroll
      for (int i = 0; i < AF; i++) {
        const int m0 = bm + wm + i * 16 + quad * 4;
#pragma unroll
        for (int r = 0; r < 4; r++) {
          float v = acc[i][j][r] + bj;
          if (rot) {
            const int s_pos = (m0 + r) & 2047;
            float rev = (float)s_pos * invrev;
            rev -= floorf(rev);
            const float sn = __builtin_amdgcn_sinf(rev);
            const float cs = __builtin_amdgcn_cosf(rev);
            const float partner = __shfl_xor(v, 1);
            v = (dh & 1) ? (v * cs + partner * sn) : (v * cs - partner * sn);
          }
          if (C_F32) ((float*)Cv)[(size_t)(m0 + r) * N + n] = v;
          else       ((uint16_t*)Cv)[(size_t)(m0 + r) * N + n] = f2bf(v);
        }
      }
    }
  }
}

// Flash attention, causal, MAX-FREE softmax (scores statically bounded ->
// exp finite; masked lanes -1e30 -> exp=0). S^T form: lane l16 owns q-row
// l16; P pack = 4x ds_write_b64; one scalar row-sum per frag.
// R15: QBLK 128 -> 64 (one 16-row frag per wave). R4 counters: occupancy
// 11%, all pipes <30% -> concurrency-bound; grid 512 (2 blocks/CU) was the
// limit while LDS allowed 4+. Now 1024 blocks = 4/CU, LDS 25.6KB (6/CU
// capacity). kt-iterations double but per-kt compute halves (same MFMA/exp
// totals); staging doubles but K/V is L2-resident (HBM was 4%).
// XCD swizzle: bx&7 = XCD; 4 heads/XCD -> 2 MB K/VT L2-resident.
// Heaviest q-tiles dispatched first.
__global__ __launch_bounds__(256) void flash_kernel(const uint16_t* __restrict__ Q,
                                                    const uint16_t* __restrict__ K,
                                                    const uint16_t* __restrict__ VT,
                                                    uint16_t* __restrict__ AO) {
  const int bx = blockIdx.x;           // 1024 blocks
  const int xcd = bx & 7;
  const int slot = bx >> 3;            // 0..127
  const int bh = (slot >> 5) * 8 + xcd;
  const int qt = 31 - (slot & 31);     // heaviest first
  const int h = bh & 15;
  const int b = bh >> 4;
  const int tid = threadIdx.x;
  const int wave = tid >> 6, lane = tid & 63;
  const int quad = lane >> 4, l16 = lane & 15;

  __shared__ __align__(16) uint16_t Ks[64 * 64];      // [n][d] swizzled, 8KB
  __shared__ __align__(16) uint16_t Vt[64 * 64];      // [d][n] swizzled, 8KB
  __shared__ __align__(16) uint16_t Ps[4][16 * 72];   // per-wave P, 9KB

  // Q fragment (B-operand layout: lane l16 = q-row), pre-scaled by 1/8
  const int qrow = qt * 64 + wave * 16 + l16;
  bf16x8 qf[2];
#pragma unroll
  for (int s = 0; s < 2; s++) {
    union { bf16x8 v; uint16_t u[8]; } t0;
    t0.v = *(const bf16x8*)(Q + ((size_t)(b * 2048 + qrow) * 1024) + h * 64 + s * 32 + quad * 8);
#pragma unroll
    for (int j = 0; j < 8; j++) t0.u[j] = f2bf(bf2f(t0.u[j]) * 0.125f);
    qf[s] = t0.v;
  }

  const size_t vbase = ((size_t)((b * 16 + h) * 64)) * 2048;  // VT head base

  float lsum = 0.f;
  f32x4 o[4] = {};

  const int nkt = qt + 1;
  for (int kt = 0; kt < nkt; kt++) {
    if (kt) __syncthreads();
#pragma unroll
    for (int i = 0; i < 2; i++) {
      const int c = i * 256 + tid;
      const int r = c >> 3, pc = ((c & 7) ^ (r & 7)) << 3;
      async_copy16(K + ((size_t)(b * 2048 + kt * 64 + r) * 1024) + h * 64 + pc,
                   Ks + (i * 256 + (tid & 192)) * 8);
      async_copy16(VT + vbase + (size_t)r * 2048 + kt * 64 + pc,
                   Vt + (i * 256 + (tid & 192)) * 8);
    }
    __syncthreads();

    // ---- S^T = K q^T (lane l16 owns q-row qrow) ----
    f32x4 sacc[4] = {};
#pragma unroll
    for (int s = 0; s < 2; s++)
#pragma unroll
      for (int t = 0; t < 4; t++) {
        const int R = t * 16 + l16;
        bf16x8 kf = *(const bf16x8*)(Ks + R * 64 + (((s * 4 + quad) ^ (R & 7)) << 3));
        sacc[t] = __builtin_amdgcn_mfma_f32_16x16x32_bf16(kf, qf[s], sacc[t], 0, 0, 0);
      }
    if (kt == qt) {  // diagonal tile: causal mask
#pragma unroll
      for (int t = 0; t < 4; t++)
#pragma unroll
        for (int r = 0; r < 4; r++)
          if (kt * 64 + t * 16 + quad * 4 + r > qrow) sacc[t][r] = -1e30f;
    }
#pragma unroll
    for (int t = 0; t < 4; t++) {
      float p0 = __expf(sacc[t][0]), p1 = __expf(sacc[t][1]);
      float p2 = __expf(sacc[t][2]), p3 = __expf(sacc[t][3]);
      lsum += (p0 + p1) + (p2 + p3);
      uint2 pk;
      pk.x = (unsigned)f2bf(p0) | ((unsigned)f2bf(p1) << 16);
      pk.y = (unsigned)f2bf(p2) | ((unsigned)f2bf(p3) << 16);
      *(uint2*)(&Ps[wave][l16 * 72 + t * 16 + quad * 4]) = pk;
    }
    // ---- PV ----
#pragma unroll
    for (int s = 0; s < 2; s++) {
      const bf16x8 pa = *(const bf16x8*)(&Ps[wave][l16 * 72 + s * 32 + quad * 8]);
#pragma unroll
      for (int t = 0; t < 4; t++) {
        const int R = t * 16 + l16;
        const bf16x8 vb = *(const bf16x8*)(Vt + R * 64 + (((s * 4 + quad) ^ (R & 7)) << 3));
        o[t] = __builtin_amdgcn_mfma_f32_16x16x32_bf16(pa, vb, o[t], 0, 0, 0);
      }
    }
  }
  // row-sum reduce over quads (q-row = l16); broadcast inverse to C/D rows
  lsum += __shfl_xor(lsum, 16);
  lsum += __shfl_xor(lsum, 32);
  const float inv = 1.f / lsum;
  float invr[4];
#pragma unroll
  for (int r = 0; r < 4; r++) invr[r] = __shfl(inv, quad * 4 + r);
#pragma unroll
  for (int t = 0; t < 4; t++)
#pragma unroll
    for (int r = 0; r < 4; r++) {
      const int qg = qt * 64 + wave * 16 + quad * 4 + r;
      AO[((size_t)(b * 2048 + qg) * 1024) + h * 64 + t * 16 + l16] =
          f2bf(o[t][r] * invr[r]);
    }
}

extern "C" void kernel_launch(void* const* d_in, const int* in_sizes, int n_in,
                              void* d_out, int out_size, void* d_ws, size_t ws_size,
                              hipStream_t stream) {
  const float* query = (const float*)d_in[0];
  const float* key   = (const float*)d_in[1];
  const float* value = (const float*)d_in[2];
  const float* Wq = (const float*)d_in[3];
  const float* bq = (const float*)d_in[4];
  const float* Wk = (const float*)d_in[5];
  const float* bk = (const float*)d_in[6];
  const float* Wv = (const float*)d_in[7];
  const float* bv = (const float*)d_in[8];
  const float* Wo = (const float*)d_in[9];
  const float* bo = (const float*)d_in[10];
  float* out = (float*)d_out;

  uint16_t* ws = (uint16_t*)d_ws;
  uint16_t* Qb  = ws;                         // [0,8M) bytes: bf16 (roped)
  uint16_t* Kb  = ws + (size_t)4194304;       // [8M,16M) (roped)
  uint16_t* VTb = ws + (size_t)8388608;       // [16M,24M) V^T [b,h,d,s]
  uint16_t* AOb = ws + (size_t)12582912;      // [24M,32M)

  dim3 blk(256);

  if (ws_size >= (size_t)64 * 1024 * 1024) {
    // Fast path: bf16 copies of activations + all weights -> pure-DMA GEMMs.
    uint16_t* Qc  = ws + (size_t)16777216;    // [32M,40M) query bf16
    uint16_t* Kc  = ws + (size_t)20971520;    // [40M,48M) key bf16
    uint16_t* Vc  = ws + (size_t)25165824;    // [48M,56M) value bf16
    uint16_t* Wqc = ws + (size_t)29360128;    // [56M,58M)
    uint16_t* Wkc = ws + (size_t)30408704;    // [58M,60M)
    uint16_t* Wvc = ws + (size_t)31457280;    // [60M,62M)
    uint16_t* Woc = ws + (size_t)32505856;    // [62M,64M)

    cvt_kernel<<<dim3(512, 1, 4), blk, 0, stream>>>(
        Wq, Wqc, Wk, Wkc, Wv, Wvc, Wo, Woc);
    cvt_kernel<<<dim3(2048, 1, 3), blk, 0, stream>>>(
        query, Qc, key, Kc, value, Vc, nullptr, nullptr);
    // QKV: pure bf16, 128x128 tile, both operands global_load_lds,
    // 32KB LDS -> 5 blocks/CU; grid 8 n-tiles x 32 m-tiles x 3
    gemm3_kernel<false, false, false, true, true, 128, 4><<<dim3(8, 32, 3), blk, 0, stream>>>(
        Qc, Wqc, bq, Qb,
        Kc, Wkc, bk, Kb,
        Vc, Wvc, bv, VTb,
        4096, 1024, 1024);
    flash_kernel<<<dim3(1024), blk, 0, stream>>>(Qb, Kb, VTb, AOb);
    // out-proj: pure bf16 128x64, both DMA, 24KB LDS -> 6 blocks/CU
    gemm3_kernel<false, false, true, false, false, 128, 2><<<dim3(16, 32, 1), blk, 0, stream>>>(
        AOb, Woc, bo, out,
        AOb, Woc, bo, out,
        AOb, Woc, bo, out,
        4096, 1024, 1024);
  } else {
    // Fallback: R0 GEMM configuration (32MB workspace).
    uint16_t* Wqc = AOb;
    uint16_t* Wkc = AOb + (size_t)1048576;
    uint16_t* Wvc = AOb + (size_t)2097152;
    cvt_kernel<<<dim3(512, 1, 3), blk, 0, stream>>>(
        Wq, Wqc, Wk, Wkc, Wv, Wvc, nullptr, nullptr);
    gemm3_kernel<true, false, false, true, true, 128, 2><<<dim3(16, 32, 3), blk, 0, stream>>>(
        query, Wqc, bq, Qb,
        key,   Wkc, bk, Kb,
        value, Wvc, bv, VTb,
        4096, 1024, 1024);
    flash_kernel<<<dim3(1024), blk, 0, stream>>>(Qb, Kb, VTb, AOb);
    gemm3_kernel<false, true, true, false, false, 128, 2><<<dim3(16, 32, 1), blk, 0, stream>>>(
        AOb, Wo, bo, out,
        AOb, Wo, bo, out,
        AOb, Wo, bo, out,
        4096, 1024, 1024);
  }
}